// Round 3
// baseline (256.312 us; speedup 1.0000x reference)
//
#include <hip/hip_runtime.h>
#include <cstdint>
#include <cstddef>

#define M_DIM 4096   // B*S
#define N_DIM 4096   // DOUT
#define K_DIM 4096   // DIN
#define BM 256
#define BN 256
#define BKB 128      // K-tile in BYTES (= 128 i8 elems); 128B LDS rows
#define KTILES (K_DIM / BKB)

typedef __attribute__((ext_vector_type(4))) int i32x4;
typedef __attribute__((ext_vector_type(16))) int i32x16;

// async global->LDS, 16B per lane. LDS dest is wave-uniform base + lane*16.
__device__ __forceinline__ void async_copy16(const void* g, void* l) {
  __builtin_amdgcn_global_load_lds(
      (const __attribute__((address_space(1))) void*)g,
      (__attribute__((address_space(3))) void*)l,
      16, 0, 0);
}

__device__ __forceinline__ void wait_vm6() {
  asm volatile("s_waitcnt vmcnt(6)" ::: "memory");
}
__device__ __forceinline__ void wait_vm4() {
  asm volatile("s_waitcnt vmcnt(4)" ::: "memory");
}
__device__ __forceinline__ void wait_vm2() {
  asm volatile("s_waitcnt vmcnt(2)" ::: "memory");
}
__device__ __forceinline__ void wait_vm0() {
  asm volatile("s_waitcnt vmcnt(0)" ::: "memory");
}
__device__ __forceinline__ void wait_none() {}

// ---------------------------------------------------------------------------
// Kernel 1: per-row int8 quantization of x. One block per row (4096 rows).
// ---------------------------------------------------------------------------
__global__ __launch_bounds__(256) void convert_x_kernel(
    const float* __restrict__ x, signed char* __restrict__ xi,
    float* __restrict__ sx, float* __restrict__ rs) {
  __shared__ float red[8];
  const int t = threadIdx.x;
  const size_t row = blockIdx.x;
  const float* xr = x + row * (size_t)K_DIM;

  float4 v[4];
  float amax = 0.f;
#pragma unroll
  for (int i = 0; i < 4; ++i) {
    v[i] = *(const float4*)(xr + (i * 256 + t) * 4);
    amax = fmaxf(amax, fmaxf(fmaxf(fabsf(v[i].x), fabsf(v[i].y)),
                             fmaxf(fabsf(v[i].z), fabsf(v[i].w))));
  }
#pragma unroll
  for (int o = 32; o > 0; o >>= 1)
    amax = fmaxf(amax, __shfl_down(amax, o, 64));
  if ((t & 63) == 0) red[t >> 6] = amax;
  __syncthreads();
  amax = fmaxf(fmaxf(fmaxf(red[0], red[1]), fmaxf(red[2], red[3])), 1e-20f);
  const float inv = 127.f / amax;

  int ssum = 0;
  signed char* out = xi + row * (size_t)K_DIM;
#pragma unroll
  for (int i = 0; i < 4; ++i) {
    const int ia = __float2int_rn(v[i].x * inv);
    const int ib = __float2int_rn(v[i].y * inv);
    const int ic = __float2int_rn(v[i].z * inv);
    const int id = __float2int_rn(v[i].w * inv);
    ssum += ia + ib + ic + id;
    const int pk =
        (ia & 255) | ((ib & 255) << 8) | ((ic & 255) << 16) | (id << 24);
    *(int*)(out + (i * 256 + t) * 4) = pk;
  }
  float fs = (float)ssum;
#pragma unroll
  for (int o = 32; o > 0; o >>= 1) fs += __shfl_down(fs, o, 64);
  if ((t & 63) == 0) red[4 + (t >> 6)] = fs;
  __syncthreads();
  if (t == 0) {
    rs[row] = red[4] + red[5] + red[6] + red[7];
    sx[row] = amax * (1.f / 127.f);
  }
}

// ---------------------------------------------------------------------------
// Kernel 2: q int32 [K][N] -> qsT int8 [N][K], value (q-128). 64x64 tile.
// ---------------------------------------------------------------------------
__global__ __launch_bounds__(256) void convert_w_kernel(
    const int* __restrict__ q, signed char* __restrict__ qsT) {
  __shared__ __align__(16) int qtile[64][68];  // 68-int rows: 16B-aligned + pad
  const int t = threadIdx.x;
  const int k0 = (blockIdx.x & 63) << 6;
  const int n0 = (blockIdx.x >> 6) << 6;

  {
    const int c = t & 15;        // n-chunk (4 ints)
    const int r0 = t >> 4;       // k-row base
#pragma unroll
    for (int i = 0; i < 4; ++i) {
      const int r = r0 + i * 16;
      const int4 v = *(const int4*)(q + (size_t)(k0 + r) * N_DIM + n0 + c * 4);
      *(int4*)&qtile[r][c * 4] = v;
    }
  }
  __syncthreads();
  {
    const int kc = t & 15;   // k-chunk: rows kc*4 .. kc*4+3
    const int g = t >> 4;    // n-group: cols g*4 .. g*4+3
    int4 v[4];
#pragma unroll
    for (int i = 0; i < 4; ++i) v[i] = *(const int4*)&qtile[kc * 4 + i][g * 4];
#pragma unroll
    for (int j = 0; j < 4; ++j) {
      const int b0 = ((&v[0].x)[j] - 128) & 255;
      const int b1 = ((&v[1].x)[j] - 128) & 255;
      const int b2 = ((&v[2].x)[j] - 128) & 255;
      const int b3 = ((&v[3].x)[j] - 128) & 255;
      const int pk = b0 | (b1 << 8) | (b2 << 16) | (b3 << 24);
      *(int*)(qsT + (size_t)(n0 + g * 4 + j) * K_DIM + k0 + kc * 4) = pk;
    }
  }
}

// ---------------------------------------------------------------------------
// Kernel 3: 256x256 i8 GEMM, counted-vmcnt schedule (T3+T4+T5), now with
// mfma_i32_32x32x32_i8 (R3 change): same fragment bytes per lane (16B chunk),
// 2x ops per instruction, higher measured rate (4404 vs 3944 TOPS), half the
// MFMA instruction count. Stage/wait/barrier ledger byte-identical to R2:
//
// Half-tile staging (16 KB = 2 global_load_lds/lane), fixed order per tile:
//   S[4t+0] = A_lo(t)  rows {0-63, 128-191}     read at phase 0 (LDA(0))
//   S[4t+1] = B_0 (t)  rows {q*64+0 .. +31}     read at phase 0 (LDB(0))
//   S[4t+2] = B_1 (t)  rows {q*64+32 .. +63}    read at phase 1 (LDB(1))
//   S[4t+3] = A_hi(t)  rows {64-127, 192-255}   read at phase 2 (LDA(1))
// Stage pointer runs 7 half-tiles ahead; per-phase vmcnt(6) keeps 3
// half-tiles in flight, never drains to 0 in the main loop. Regions die
// phase-by-phase (A_lo/B_0 after p0, B_1 after p1, A_hi after p2) so tile
// t+2's halves land in buffer t&1 while tile t computes. Deadline table
// verified in R1/R2 (passed).
//
// mfma_i32_32x32x32_i8 layouts (mirror of verified 16x16x64 i8 + m74/m101):
//   A: row = lane&31, k = (lane>>5)*16 + j, j=0..15 (one 16B chunk)
//   B: col = lane&31, k = (lane>>5)*16 + j           (from [N][K] i8)
//   C/D: col = lane&31, row = (reg&3) + 8*(reg>>2) + 4*(lane>>5), reg 0..15
// ---------------------------------------------------------------------------
__global__ __launch_bounds__(512, 2) void gemm_kernel(
    const signed char* __restrict__ A,   // [M][K] i8
    const signed char* __restrict__ Bt,  // [N][K] i8
    const float* __restrict__ bias, const float* __restrict__ sx,
    const float* __restrict__ rs, const float* __restrict__ scale_p,
    const float* __restrict__ zp_p, float* __restrict__ C) {
  __shared__ __align__(16) signed char As[2][BM * BKB];  // 2 x 32 KB
  __shared__ __align__(16) signed char Bs[2][BN * BKB];  // 2 x 32 KB

  const int tid = threadIdx.x;
  const int wave = tid >> 6;   // 0..7
  const int lane = tid & 63;
  const int wm = wave >> 2;    // 0..1  (M half)
  const int wn = wave & 3;     // 0..3  (N quarter)

  // T1: XCD-aware bijective swizzle; grid=256, 32 consecutive per XCD.
  const int swz = (blockIdx.x & 7) * 32 + (blockIdx.x >> 3);
  const int bm = swz & 15;
  const int bn = swz >> 4;
  const size_t m0 = (size_t)bm * BM;
  const size_t n0 = (size_t)bn * BN;

  // staging lane decomposition: LDS dest linear, global src pre-swizzled.
  const int srow = lane >> 3;                   // 0..7 row within 1KB issue
  const int schunk = (lane & 7) ^ srow;         // swizzled global 16B chunk

  // fragment lane decomposition (32x32)
  const int l31 = lane & 31;
  const int khalf = lane >> 5;   // selects 16B half of the 32-elem K-step

  const signed char* Abase = A + m0 * K_DIM + schunk * 16;
  const signed char* Bbase = Bt + n0 * K_DIM + schunk * 16;

  i32x16 acc[4][2];  // [m-block 0..3][n-block 0..1], per-wave 128x64
#pragma unroll
  for (int i = 0; i < 4; ++i)
#pragma unroll
    for (int j = 0; j < 2; ++j)
#pragma unroll
      for (int e = 0; e < 16; ++e) acc[i][j][e] = 0;

  // Half-tile stagers: each = 2 global_load_lds per lane (16 KB total).
  auto stageA = [&](int b, int k0, int ig) {
#pragma unroll
    for (int i = 0; i < 2; ++i) {
      const int rbase = i * 128 + ig * 64 + wave * 8;  // wave-uniform
      const size_t go = (size_t)(rbase + srow) * K_DIM + k0;
      async_copy16(Abase + go, (void*)&As[b][rbase * BKB]);
    }
  };
  auto stageB = [&](int b, int k0, int jg) {
#pragma unroll
    for (int i = 0; i < 2; ++i) {
      const int rbase = (i * 2 + (wave >> 2)) * 64 + jg * 32 + (wave & 3) * 8;
      const size_t go = (size_t)(rbase + srow) * K_DIM + k0;
      async_copy16(Bbase + go, (void*)&Bs[b][rbase * BKB]);
    }
  };

  // Fragment reads. Stored chunk = logical ^ (row&7) (conflict-free, 0
  // measured). Logical chunk for K-step ks = ks*2 + khalf.
#define LDA(ig)                                                              \
  do {                                                                       \
    _Pragma("unroll") for (int ks = 0; ks < 4; ++ks)                         \
        _Pragma("unroll") for (int m = 0; m < 2; ++m) {                      \
      const int ar = wm * 128 + (ig) * 64 + m * 32 + l31;                    \
      av[ks][m] = *(const i32x4*)(as + ar * BKB +                            \
                                  ((((ks << 1) | khalf) ^ (ar & 7)) << 4));  \
    }                                                                        \
  } while (0)

#define LDB(nb)                                                              \
  do {                                                                       \
    _Pragma("unroll") for (int ks = 0; ks < 4; ++ks) {                       \
      const int br = wn * 64 + (nb) * 32 + l31;                              \
      bv[ks][nb] = *(const i32x4*)(bs + br * BKB +                           \
                                   ((((ks << 1) | khalf) ^ (br & 7)) << 4)); \
    }                                                                        \
  } while (0)

  // 8 MFMA per phase: one (A-half x B-quarter) quadrant over 4 K-steps.
#define MFMA8(ihalf, nb)                                                     \
  do {                                                                       \
    __builtin_amdgcn_s_setprio(1);                                           \
    _Pragma("unroll") for (int ks = 0; ks < 4; ++ks)                         \
        _Pragma("unroll") for (int m = 0; m < 2; ++m)                        \
        acc[(ihalf) * 2 + m][nb] = __builtin_amdgcn_mfma_i32_32x32x32_i8(    \
            av[ks][m], bv[ks][nb], acc[(ihalf) * 2 + m][nb], 0, 0, 0);       \
    __builtin_amdgcn_s_setprio(0);                                           \
  } while (0)

#define DO_TILE(AS, BS, S0, W0, S1, W1, S2, W2, S3)                          \
  do {                                                                       \
    const signed char* as = (AS);                                            \
    const signed char* bs = (BS);                                            \
    i32x4 av[4][2], bv[4][2];                                                \
    LDA(0);                                                                  \
    LDB(0);                                                                  \
    S0;                                                                      \
    W0();                                                                    \
    __builtin_amdgcn_s_barrier();                                            \
    MFMA8(0, 0);                                                             \
    __builtin_amdgcn_s_barrier();                                            \
    LDB(1);                                                                  \
    S1;                                                                      \
    W1();                                                                    \
    __builtin_amdgcn_s_barrier();                                            \
    MFMA8(0, 1);                                                             \
    __builtin_amdgcn_s_barrier();                                            \
    LDA(1);                                                                  \
    S2;                                                                      \
    W2();                                                                    \
    __builtin_amdgcn_s_barrier();                                            \
    MFMA8(1, 1);                                                             \
    __builtin_amdgcn_s_barrier();                                            \
    S3;                                                                      \
    MFMA8(1, 0);                                                             \
  } while (0)

  // Prologue: stage S[0..6] (tile0 all + tile1 {A_lo,B_0,B_1}), wait, barrier.
  stageA(0, 0, 0);
  stageB(0, 0, 0);
  stageB(0, 0, 1);
  stageA(0, 0, 1);
  stageA(1, BKB, 0);
  stageB(1, BKB, 0);
  stageB(1, BKB, 1);
  wait_vm6();
  __builtin_amdgcn_s_barrier();

#pragma unroll 2
  for (int kt = 0; kt < KTILES - 2; ++kt) {
    const int buf = kt & 1;
    const int k1 = (kt + 1) * BKB;
    const int k2 = (kt + 2) * BKB;
    DO_TILE(As[buf], Bs[buf],
            (stageA(buf ^ 1, k1, 1)), wait_vm6,   // S[4t+7]  = A_hi(t+1)
            (stageA(buf, k2, 0)),     wait_vm6,   // S[4t+8]  = A_lo(t+2)
            (stageB(buf, k2, 0)),     wait_vm6,   // S[4t+9]  = B_0 (t+2)
            (stageB(buf, k2, 1)));                // S[4t+10] = B_1 (t+2)
  }

  // Tail: tile 30 (stage last half = A_hi(31); drain 6->4->2), tile 31.
  DO_TILE(As[0], Bs[0], (stageA(1, 31 * BKB, 1)), wait_vm6, (void)0, wait_vm4,
          (void)0, wait_vm2, (void)0);
  DO_TILE(As[1], Bs[1], (void)0, wait_vm0, (void)0, wait_none, (void)0,
          wait_none, (void)0);

#undef LDA
#undef LDB
#undef MFMA8
#undef DO_TILE

  // Epilogue: y = a_m*accf + b_m + bias[n], a_m = scale*sx[m],
  // b_m = scale*sx[m]*(128-zp)*rs[m].
  // 32x32 C/D: col = l31, row = (reg&3) + 8*(reg>>2) + 4*khalf.
  const float scale = scale_p[0];
  const float c1 = 128.f - zp_p[0];
#pragma unroll
  for (int mb = 0; mb < 4; ++mb) {
#pragma unroll
    for (int q = 0; q < 4; ++q) {
      const size_t mbase = m0 + wm * 128 + mb * 32 + q * 8 + khalf * 4;
      float am[4], bmv[4];
#pragma unroll
      for (int r = 0; r < 4; ++r) {
        const float a = scale * sx[mbase + r];
        am[r] = a;
        bmv[r] = a * c1 * rs[mbase + r];
      }
#pragma unroll
      for (int nb = 0; nb < 2; ++nb) {
        const size_t n = n0 + wn * 64 + nb * 32 + l31;
        const float bvv = bias[n];
#pragma unroll
        for (int r = 0; r < 4; ++r) {
          C[(mbase + r) * N_DIM + n] =
              fmaf(am[r], (float)acc[mb][nb][q * 4 + r], bmv[r] + bvv);
        }
      }
    }
  }
}

// ---------------------------------------------------------------------------
extern "C" void kernel_launch(void* const* d_in, const int* in_sizes, int n_in,
                              void* d_out, int out_size, void* d_ws,
                              size_t ws_size, hipStream_t stream) {
  const float* x = (const float*)d_in[0];
  const int* q = (const int*)d_in[1];
  const float* scale = (const float*)d_in[2];
  const float* zp = (const float*)d_in[3];
  const float* bias = (const float*)d_in[4];
  float* out = (float*)d_out;

  char* ws = (char*)d_ws;
  signed char* xi = (signed char*)ws;                           // 16 MB
  signed char* qsT = (signed char*)(ws + ((size_t)16 << 20));   // 16 MB
  float* sx = (float*)(ws + ((size_t)32 << 20));                // 16 KB
  float* rs = (float*)(ws + ((size_t)32 << 20) + (16 << 10));   // 16 KB

  convert_x_kernel<<<4096, 256, 0, stream>>>(x, xi, sx, rs);
  convert_w_kernel<<<4096, 256, 0, stream>>>(q, qsT);
  gemm_kernel<<<256, 512, 0, stream>>>(xi, qsT, bias, sx, rs, scale, zp, out);
}

// Round 4
// 241.863 us; speedup vs baseline: 1.0597x; 1.0597x over previous
//
#include <hip/hip_runtime.h>
#include <cstdint>
#include <cstddef>

#define M_DIM 4096   // B*S
#define N_DIM 4096   // DOUT
#define K_DIM 4096   // DIN
#define BM 256
#define BN 256
#define BKB 128      // K-tile in BYTES (= 128 i8 elems); 128B LDS rows
#define KTILES (K_DIM / BKB)

typedef __attribute__((ext_vector_type(4))) int i32x4;

// async global->LDS, 16B per lane. LDS dest is wave-uniform base + lane*16.
__device__ __forceinline__ void async_copy16(const void* g, void* l) {
  __builtin_amdgcn_global_load_lds(
      (const __attribute__((address_space(1))) void*)g,
      (__attribute__((address_space(3))) void*)l,
      16, 0, 0);
}

__device__ __forceinline__ void wait_vm6() {
  asm volatile("s_waitcnt vmcnt(6)" ::: "memory");
}
__device__ __forceinline__ void wait_vm0() {
  asm volatile("s_waitcnt vmcnt(0)" ::: "memory");
}

// ---------------------------------------------------------------------------
// Kernel 1: per-row int8 quantization of x. One block per row (4096 rows).
// ---------------------------------------------------------------------------
__global__ __launch_bounds__(256) void convert_x_kernel(
    const float* __restrict__ x, signed char* __restrict__ xi,
    float* __restrict__ sx, float* __restrict__ rs) {
  __shared__ float red[8];
  const int t = threadIdx.x;
  const size_t row = blockIdx.x;
  const float* xr = x + row * (size_t)K_DIM;

  float4 v[4];
  float amax = 0.f;
#pragma unroll
  for (int i = 0; i < 4; ++i) {
    v[i] = *(const float4*)(xr + (i * 256 + t) * 4);
    amax = fmaxf(amax, fmaxf(fmaxf(fabsf(v[i].x), fabsf(v[i].y)),
                             fmaxf(fabsf(v[i].z), fabsf(v[i].w))));
  }
#pragma unroll
  for (int o = 32; o > 0; o >>= 1)
    amax = fmaxf(amax, __shfl_down(amax, o, 64));
  if ((t & 63) == 0) red[t >> 6] = amax;
  __syncthreads();
  amax = fmaxf(fmaxf(fmaxf(red[0], red[1]), fmaxf(red[2], red[3])), 1e-20f);
  const float inv = 127.f / amax;

  int ssum = 0;
  signed char* out = xi + row * (size_t)K_DIM;
#pragma unroll
  for (int i = 0; i < 4; ++i) {
    const int ia = __float2int_rn(v[i].x * inv);
    const int ib = __float2int_rn(v[i].y * inv);
    const int ic = __float2int_rn(v[i].z * inv);
    const int id = __float2int_rn(v[i].w * inv);
    ssum += ia + ib + ic + id;
    const int pk =
        (ia & 255) | ((ib & 255) << 8) | ((ic & 255) << 16) | (id << 24);
    *(int*)(out + (i * 256 + t) * 4) = pk;
  }
  float fs = (float)ssum;
#pragma unroll
  for (int o = 32; o > 0; o >>= 1) fs += __shfl_down(fs, o, 64);
  if ((t & 63) == 0) red[4 + (t >> 6)] = fs;
  __syncthreads();
  if (t == 0) {
    rs[row] = red[4] + red[5] + red[6] + red[7];
    sx[row] = amax * (1.f / 127.f);
  }
}

// ---------------------------------------------------------------------------
// Kernel 2: q int32 [K][N] -> qsT int8 [N][K], value (q-128). 64x64 tile.
// ---------------------------------------------------------------------------
__global__ __launch_bounds__(256) void convert_w_kernel(
    const int* __restrict__ q, signed char* __restrict__ qsT) {
  __shared__ __align__(16) int qtile[64][68];  // 68-int rows: 16B-aligned + pad
  const int t = threadIdx.x;
  const int k0 = (blockIdx.x & 63) << 6;
  const int n0 = (blockIdx.x >> 6) << 6;

  {
    const int c = t & 15;        // n-chunk (4 ints)
    const int r0 = t >> 4;       // k-row base
#pragma unroll
    for (int i = 0; i < 4; ++i) {
      const int r = r0 + i * 16;
      const int4 v = *(const int4*)(q + (size_t)(k0 + r) * N_DIM + n0 + c * 4);
      *(int4*)&qtile[r][c * 4] = v;
    }
  }
  __syncthreads();
  {
    const int kc = t & 15;   // k-chunk: rows kc*4 .. kc*4+3
    const int g = t >> 4;    // n-group: cols g*4 .. g*4+3
    int4 v[4];
#pragma unroll
    for (int i = 0; i < 4; ++i) v[i] = *(const int4*)&qtile[kc * 4 + i][g * 4];
#pragma unroll
    for (int j = 0; j < 4; ++j) {
      const int b0 = ((&v[0].x)[j] - 128) & 255;
      const int b1 = ((&v[1].x)[j] - 128) & 255;
      const int b2 = ((&v[2].x)[j] - 128) & 255;
      const int b3 = ((&v[3].x)[j] - 128) & 255;
      const int pk = b0 | (b1 << 8) | (b2 << 16) | (b3 << 24);
      *(int*)(qsT + (size_t)(n0 + g * 4 + j) * K_DIM + k0 + kc * 4) = pk;
    }
  }
}

// ---------------------------------------------------------------------------
// Kernel 3: 256x256 i8 GEMM, 16x16x64 (R2-verified shape, 0 conflicts),
// counted-vmcnt ledger (R2-verified), R4 change: barrier-light tile.
//
// Ledger (unchanged from R2): half-tile staging, order per tile t:
//   S[4t+0]=A_lo(t)  S[4t+1]=B_0(t)  S[4t+2]=B_1(t)  S[4t+3]=A_hi(t)
// stages at tile t: S0=A_hi(t+1)->buf^1, S1=A_lo(t+2)->buf, S2=B_0(t+2),
// S3=B_1(t+2). Stage ptr 7 half-tiles ahead; tile-top wait vmcnt(6) ->
// landed through S[4t+4] => ALL of tile t resident at tile top (proved R2).
//
// R4 restructure: since the whole tile is resident at top, issue 16 ds_reads
// (A_lo,B0,B1) at tile top and A_hi's 8 after p1 (reusing A_lo's regs ->
// operand VGPRs stay 64). 4 barriers/tile (was 7), 1 vmcnt (was 3); each
// barrier is the WAR fence for exactly one stage:
//   post-p0: A_lo reads data-consumed by p0 MFMA => lgkm drained => S1 safe
//   post-p1: B_1 consumed by p1 => (S2 overwrites B_0, consumed p0) safe
//   post-p2: S3 overwrites B_1, consumed p1, safe
// Cross-wave residency: every wave waits vmcnt(6) BEFORE the top barrier with
// an identical ledger => after barrier, tile resident for all waves.
// p1/p3 MFMAs have zero lgkm dependence -> LDS reads overlap MFMA issue.
// ---------------------------------------------------------------------------
__global__ __launch_bounds__(512, 2) void gemm_kernel(
    const signed char* __restrict__ A,   // [M][K] i8
    const signed char* __restrict__ Bt,  // [N][K] i8
    const float* __restrict__ bias, const float* __restrict__ sx,
    const float* __restrict__ rs, const float* __restrict__ scale_p,
    const float* __restrict__ zp_p, float* __restrict__ C) {
  __shared__ __align__(16) signed char As[2][BM * BKB];  // 2 x 32 KB
  __shared__ __align__(16) signed char Bs[2][BN * BKB];  // 2 x 32 KB

  const int tid = threadIdx.x;
  const int wave = tid >> 6;   // 0..7
  const int lane = tid & 63;
  const int wm = wave >> 2;    // 0..1  (M half)
  const int wn = wave & 3;     // 0..3  (N quarter)

  // T1: XCD-aware bijective swizzle; grid=256, 32 consecutive per XCD.
  const int swz = (blockIdx.x & 7) * 32 + (blockIdx.x >> 3);
  const int bm = swz & 15;
  const int bn = swz >> 4;
  const size_t m0 = (size_t)bm * BM;
  const size_t n0 = (size_t)bn * BN;

  // staging lane decomposition: LDS dest linear, global src pre-swizzled.
  const int srow = lane >> 3;                   // 0..7 row within 1KB issue
  const int schunk = (lane & 7) ^ srow;         // swizzled global 16B chunk

  // fragment lane decomposition (16x16x64)
  const int quad = lane >> 4;
  const int lrow = lane & 15;
  const int rsw = lrow & 7;

  const signed char* Abase = A + m0 * K_DIM + schunk * 16;
  const signed char* Bbase = Bt + n0 * K_DIM + schunk * 16;

  i32x4 acc[8][4];
  const i32x4 zero = {0, 0, 0, 0};
#pragma unroll
  for (int i = 0; i < 8; ++i)
#pragma unroll
    for (int j = 0; j < 4; ++j) acc[i][j] = zero;

  // Half-tile stagers: each = 2 global_load_lds per lane (16 KB total).
  auto stageA = [&](int b, int k0, int ig) {
#pragma unroll
    for (int i = 0; i < 2; ++i) {
      const int rbase = i * 128 + ig * 64 + wave * 8;  // wave-uniform
      const size_t go = (size_t)(rbase + srow) * K_DIM + k0;
      async_copy16(Abase + go, (void*)&As[b][rbase * BKB]);
    }
  };
  auto stageB = [&](int b, int k0, int jg) {
#pragma unroll
    for (int i = 0; i < 2; ++i) {
      const int rbase = (i * 2 + (wave >> 2)) * 64 + jg * 32 + (wave & 3) * 8;
      const size_t go = (size_t)(rbase + srow) * K_DIM + k0;
      async_copy16(Bbase + go, (void*)&Bs[b][rbase * BKB]);
    }
  };

#define LDA(ig)                                                              \
  do {                                                                       \
    _Pragma("unroll") for (int kh = 0; kh < 2; ++kh)                         \
        _Pragma("unroll") for (int t = 0; t < 4; ++t) {                      \
      const int ar = wm * 128 + (ig) * 64 + t * 16 + lrow;                   \
      av[kh][t] =                                                            \
          *(const i32x4*)(as + ar * BKB + ((((kh << 2) | quad) ^ rsw) << 4));\
    }                                                                        \
  } while (0)

#define LDB(jg)                                                              \
  do {                                                                       \
    _Pragma("unroll") for (int kh = 0; kh < 2; ++kh)                         \
        _Pragma("unroll") for (int t = 0; t < 2; ++t) {                      \
      const int br = wn * 64 + ((jg) * 2 + t) * 16 + lrow;                   \
      bv[kh][(jg) * 2 + t] =                                                 \
          *(const i32x4*)(bs + br * BKB + ((((kh << 2) | quad) ^ rsw) << 4));\
    }                                                                        \
  } while (0)

#define MFMA16(ibase, j0)                                                    \
  do {                                                                       \
    __builtin_amdgcn_s_setprio(1);                                           \
    _Pragma("unroll") for (int kh = 0; kh < 2; ++kh)                         \
        _Pragma("unroll") for (int t = 0; t < 4; ++t)                        \
            _Pragma("unroll") for (int j = 0; j < 2; ++j)                    \
        acc[(ibase) + t][(j0) + j] = __builtin_amdgcn_mfma_i32_16x16x64_i8(  \
            af_mfma(t, kh), bv[kh][(j0) + j], acc[(ibase) + t][(j0) + j], 0, \
            0, 0);                                                           \
    __builtin_amdgcn_s_setprio(0);                                           \
  } while (0)
#define af_mfma(t, kh) av[kh][t]

  // One tile, barrier-light. TOPW = tile-top vmcnt wait. S0..S3 = stages.
  // av holds A_lo for p0/p1, then is overwritten (WAR reg dep) with A_hi
  // for p2/p3.
#define DO_TILE(AS, BS, TOPW, S0, S1, S2, S3)                                \
  do {                                                                       \
    const signed char* as = (AS);                                            \
    const signed char* bs = (BS);                                            \
    i32x4 av[2][4], bv[2][4];                                                \
    TOPW();                                                                  \
    __builtin_amdgcn_s_barrier();                                            \
    LDA(0);                                                                  \
    LDB(0);                                                                  \
    LDB(1);                                                                  \
    S0;                                                                      \
    MFMA16(0, 0); /* p0: A_lo x B0 */                                        \
    __builtin_amdgcn_s_barrier();                                            \
    S1;                                                                      \
    MFMA16(0, 2); /* p1: A_lo x B1 */                                        \
    LDA(1);       /* overwrite av with A_hi (issues after p1 by reg WAR) */  \
    __builtin_amdgcn_s_barrier();                                            \
    S2;                                                                      \
    MFMA16(4, 2); /* p2: A_hi x B1 */                                        \
    __builtin_amdgcn_s_barrier();                                            \
    S3;                                                                      \
    MFMA16(4, 0); /* p3: A_hi x B0 */                                        \
  } while (0)

  // Prologue: stage S[0..6] = tile0 {A_lo,B_0,B_1,A_hi} + tile1
  // {A_lo,B_0,B_1}. Tile 0's top wait/barrier handles the sync.
  stageA(0, 0, 0);
  stageB(0, 0, 0);
  stageB(0, 0, 1);
  stageA(0, 0, 1);
  stageA(1, BKB, 0);
  stageB(1, BKB, 0);
  stageB(1, BKB, 1);

#pragma unroll 2
  for (int kt = 0; kt < KTILES - 2; ++kt) {
    const int buf = kt & 1;
    const int k1 = (kt + 1) * BKB;
    const int k2 = (kt + 2) * BKB;
    DO_TILE(As[buf], Bs[buf], wait_vm6,
            (stageA(buf ^ 1, k1, 1)),   // S[4t+7]  = A_hi(t+1)
            (stageA(buf, k2, 0)),       // S[4t+8]  = A_lo(t+2)
            (stageB(buf, k2, 0)),       // S[4t+9]  = B_0 (t+2)
            (stageB(buf, k2, 1)));      // S[4t+10] = B_1 (t+2)
  }

  // Tail: tile 30 (stage only S0 = A_hi(31) = S[127]; top wait vmcnt(6)
  // valid: 254 units issued, need through 248), tile 31 (wait vmcnt(0)).
  DO_TILE(As[0], Bs[0], wait_vm6, (stageA(1, 31 * BKB, 1)), (void)0, (void)0,
          (void)0);
  DO_TILE(As[1], Bs[1], wait_vm0, (void)0, (void)0, (void)0, (void)0);

#undef LDA
#undef LDB
#undef MFMA16
#undef af_mfma
#undef DO_TILE

  // Epilogue: y = a_m*accf + b_m + bias[n], a_m = scale*sx[m],
  // b_m = scale*sx[m]*(128-zp)*rs[m].
  const float scale = scale_p[0];
  const float c1 = 128.f - zp_p[0];
#pragma unroll
  for (int i = 0; i < 8; ++i) {
    const size_t mbase = m0 + wm * 128 + i * 16 + quad * 4;
    float am[4], bmv[4];
#pragma unroll
    for (int r = 0; r < 4; ++r) {
      const float a = scale * sx[mbase + r];
      am[r] = a;
      bmv[r] = a * c1 * rs[mbase + r];
    }
#pragma unroll
    for (int j = 0; j < 4; ++j) {
      const size_t n = n0 + wn * 64 + j * 16 + lrow;
      const float bv = bias[n];
#pragma unroll
      for (int r = 0; r < 4; ++r) {
        C[(mbase + r) * N_DIM + n] =
            fmaf(am[r], (float)acc[i][j][r], bmv[r] + bv);
      }
    }
  }
}

// ---------------------------------------------------------------------------
extern "C" void kernel_launch(void* const* d_in, const int* in_sizes, int n_in,
                              void* d_out, int out_size, void* d_ws,
                              size_t ws_size, hipStream_t stream) {
  const float* x = (const float*)d_in[0];
  const int* q = (const int*)d_in[1];
  const float* scale = (const float*)d_in[2];
  const float* zp = (const float*)d_in[3];
  const float* bias = (const float*)d_in[4];
  float* out = (float*)d_out;

  char* ws = (char*)d_ws;
  signed char* xi = (signed char*)ws;                           // 16 MB
  signed char* qsT = (signed char*)(ws + ((size_t)16 << 20));   // 16 MB
  float* sx = (float*)(ws + ((size_t)32 << 20));                // 16 KB
  float* rs = (float*)(ws + ((size_t)32 << 20) + (16 << 10));   // 16 KB

  convert_x_kernel<<<4096, 256, 0, stream>>>(x, xi, sx, rs);
  convert_w_kernel<<<4096, 256, 0, stream>>>(q, qsT);
  gemm_kernel<<<256, 512, 0, stream>>>(xi, qsT, bias, sx, rs, scale, zp, out);
}

// Round 5
// 240.668 us; speedup vs baseline: 1.0650x; 1.0050x over previous
//
#include <hip/hip_runtime.h>
#include <cstdint>
#include <cstddef>

#define M_DIM 4096   // B*S
#define N_DIM 4096   // DOUT
#define K_DIM 4096   // DIN
#define BM 256
#define BN 256
#define BKB 128      // K-tile in BYTES (= 128 i8 elems); 128B LDS rows
#define KTILES (K_DIM / BKB)

typedef __attribute__((ext_vector_type(4))) int i32x4;

// async global->LDS, 16B per lane. LDS dest is wave-uniform base + lane*16.
__device__ __forceinline__ void async_copy16(const void* g, void* l) {
  __builtin_amdgcn_global_load_lds(
      (const __attribute__((address_space(1))) void*)g,
      (__attribute__((address_space(3))) void*)l,
      16, 0, 0);
}

__device__ __forceinline__ void wait_vm6() {
  asm volatile("s_waitcnt vmcnt(6)" ::: "memory");
}
__device__ __forceinline__ void wait_vm0() {
  asm volatile("s_waitcnt vmcnt(0)" ::: "memory");
}

// ---------------------------------------------------------------------------
// Fused convert kernel (R5): blocks [0,4096) run the R2-verified convert_w
// body; blocks [4096,8192) run the R2-verified convert_x body. The two
// phases are independent and memory-bound; fusing lets them share the
// machine instead of serializing on the stream, and makes the combined
// dispatch big enough to show up in the top-5 counter table.
// LDS: single 17408B buffer; w-path uses it as int[64][68], x-path as
// float red[8].
// ---------------------------------------------------------------------------
__global__ __launch_bounds__(256) void convert_fused(
    const float* __restrict__ x, signed char* __restrict__ xi,
    float* __restrict__ sx, float* __restrict__ rs,
    const int* __restrict__ q, signed char* __restrict__ qsT) {
  __shared__ __align__(16) int smem[64 * 68];  // 17408 B
  const int t = threadIdx.x;

  if (blockIdx.x < 4096) {
    // ---------------- convert_w body (verified, byte-identical logic) ------
    int(*qtile)[68] = (int(*)[68])smem;
    const int bid = blockIdx.x;
    const int k0 = (bid & 63) << 6;
    const int n0 = (bid >> 6) << 6;

    {
      const int c = t & 15;        // n-chunk (4 ints)
      const int r0 = t >> 4;       // k-row base
#pragma unroll
      for (int i = 0; i < 4; ++i) {
        const int r = r0 + i * 16;
        const int4 v =
            *(const int4*)(q + (size_t)(k0 + r) * N_DIM + n0 + c * 4);
        *(int4*)&qtile[r][c * 4] = v;
      }
    }
    __syncthreads();
    {
      const int kc = t & 15;   // k-chunk: rows kc*4 .. kc*4+3
      const int g = t >> 4;    // n-group: cols g*4 .. g*4+3
      int4 v[4];
#pragma unroll
      for (int i = 0; i < 4; ++i)
        v[i] = *(const int4*)&qtile[kc * 4 + i][g * 4];
#pragma unroll
      for (int j = 0; j < 4; ++j) {
        const int b0 = ((&v[0].x)[j] - 128) & 255;
        const int b1 = ((&v[1].x)[j] - 128) & 255;
        const int b2 = ((&v[2].x)[j] - 128) & 255;
        const int b3 = ((&v[3].x)[j] - 128) & 255;
        const int pk = b0 | (b1 << 8) | (b2 << 16) | (b3 << 24);
        *(int*)(qsT + (size_t)(n0 + g * 4 + j) * K_DIM + k0 + kc * 4) = pk;
      }
    }
  } else {
    // ---------------- convert_x body (verified, byte-identical logic) ------
    float* red = (float*)smem;
    const size_t row = blockIdx.x - 4096;
    const float* xr = x + row * (size_t)K_DIM;

    float4 v[4];
    float amax = 0.f;
#pragma unroll
    for (int i = 0; i < 4; ++i) {
      v[i] = *(const float4*)(xr + (i * 256 + t) * 4);
      amax = fmaxf(amax, fmaxf(fmaxf(fabsf(v[i].x), fabsf(v[i].y)),
                               fmaxf(fabsf(v[i].z), fabsf(v[i].w))));
    }
#pragma unroll
    for (int o = 32; o > 0; o >>= 1)
      amax = fmaxf(amax, __shfl_down(amax, o, 64));
    if ((t & 63) == 0) red[t >> 6] = amax;
    __syncthreads();
    amax = fmaxf(fmaxf(fmaxf(red[0], red[1]), fmaxf(red[2], red[3])), 1e-20f);
    const float inv = 127.f / amax;

    int ssum = 0;
    signed char* out = xi + row * (size_t)K_DIM;
#pragma unroll
    for (int i = 0; i < 4; ++i) {
      const int ia = __float2int_rn(v[i].x * inv);
      const int ib = __float2int_rn(v[i].y * inv);
      const int ic = __float2int_rn(v[i].z * inv);
      const int id = __float2int_rn(v[i].w * inv);
      ssum += ia + ib + ic + id;
      const int pk =
          (ia & 255) | ((ib & 255) << 8) | ((ic & 255) << 16) | (id << 24);
      *(int*)(out + (i * 256 + t) * 4) = pk;
    }
    float fs = (float)ssum;
#pragma unroll
    for (int o = 32; o > 0; o >>= 1) fs += __shfl_down(fs, o, 64);
    if ((t & 63) == 0) red[4 + (t >> 6)] = fs;
    __syncthreads();
    if (t == 0) {
      rs[row] = red[4] + red[5] + red[6] + red[7];
      sx[row] = amax * (1.f / 127.f);
    }
  }
}

// ---------------------------------------------------------------------------
// Kernel 3: 256x256 i8 GEMM — FROZEN from R4 (73.6 µs, MfmaUtil 39%,
// 0 bank conflicts). 16x16x64 shape, counted-vmcnt ledger, barrier-light
// tile (4 barriers + 1 vmcnt per tile). See R4 comments for the ledger
// proof; unchanged byte-for-byte this round.
// ---------------------------------------------------------------------------
__global__ __launch_bounds__(512, 2) void gemm_kernel(
    const signed char* __restrict__ A,   // [M][K] i8
    const signed char* __restrict__ Bt,  // [N][K] i8
    const float* __restrict__ bias, const float* __restrict__ sx,
    const float* __restrict__ rs, const float* __restrict__ scale_p,
    const float* __restrict__ zp_p, float* __restrict__ C) {
  __shared__ __align__(16) signed char As[2][BM * BKB];  // 2 x 32 KB
  __shared__ __align__(16) signed char Bs[2][BN * BKB];  // 2 x 32 KB

  const int tid = threadIdx.x;
  const int wave = tid >> 6;   // 0..7
  const int lane = tid & 63;
  const int wm = wave >> 2;    // 0..1  (M half)
  const int wn = wave & 3;     // 0..3  (N quarter)

  // T1: XCD-aware bijective swizzle; grid=256, 32 consecutive per XCD.
  const int swz = (blockIdx.x & 7) * 32 + (blockIdx.x >> 3);
  const int bm = swz & 15;
  const int bn = swz >> 4;
  const size_t m0 = (size_t)bm * BM;
  const size_t n0 = (size_t)bn * BN;

  // staging lane decomposition: LDS dest linear, global src pre-swizzled.
  const int srow = lane >> 3;                   // 0..7 row within 1KB issue
  const int schunk = (lane & 7) ^ srow;         // swizzled global 16B chunk

  // fragment lane decomposition (16x16x64)
  const int quad = lane >> 4;
  const int lrow = lane & 15;
  const int rsw = lrow & 7;

  const signed char* Abase = A + m0 * K_DIM + schunk * 16;
  const signed char* Bbase = Bt + n0 * K_DIM + schunk * 16;

  i32x4 acc[8][4];
  const i32x4 zero = {0, 0, 0, 0};
#pragma unroll
  for (int i = 0; i < 8; ++i)
#pragma unroll
    for (int j = 0; j < 4; ++j) acc[i][j] = zero;

  // Half-tile stagers: each = 2 global_load_lds per lane (16 KB total).
  auto stageA = [&](int b, int k0, int ig) {
#pragma unroll
    for (int i = 0; i < 2; ++i) {
      const int rbase = i * 128 + ig * 64 + wave * 8;  // wave-uniform
      const size_t go = (size_t)(rbase + srow) * K_DIM + k0;
      async_copy16(Abase + go, (void*)&As[b][rbase * BKB]);
    }
  };
  auto stageB = [&](int b, int k0, int jg) {
#pragma unroll
    for (int i = 0; i < 2; ++i) {
      const int rbase = (i * 2 + (wave >> 2)) * 64 + jg * 32 + (wave & 3) * 8;
      const size_t go = (size_t)(rbase + srow) * K_DIM + k0;
      async_copy16(Bbase + go, (void*)&Bs[b][rbase * BKB]);
    }
  };

#define LDA(ig)                                                              \
  do {                                                                       \
    _Pragma("unroll") for (int kh = 0; kh < 2; ++kh)                         \
        _Pragma("unroll") for (int t = 0; t < 4; ++t) {                      \
      const int ar = wm * 128 + (ig) * 64 + t * 16 + lrow;                   \
      av[kh][t] =                                                            \
          *(const i32x4*)(as + ar * BKB + ((((kh << 2) | quad) ^ rsw) << 4));\
    }                                                                        \
  } while (0)

#define LDB(jg)                                                              \
  do {                                                                       \
    _Pragma("unroll") for (int kh = 0; kh < 2; ++kh)                         \
        _Pragma("unroll") for (int t = 0; t < 2; ++t) {                      \
      const int br = wn * 64 + ((jg) * 2 + t) * 16 + lrow;                   \
      bv[kh][(jg) * 2 + t] =                                                 \
          *(const i32x4*)(bs + br * BKB + ((((kh << 2) | quad) ^ rsw) << 4));\
    }                                                                        \
  } while (0)

#define MFMA16(ibase, j0)                                                    \
  do {                                                                       \
    __builtin_amdgcn_s_setprio(1);                                           \
    _Pragma("unroll") for (int kh = 0; kh < 2; ++kh)                         \
        _Pragma("unroll") for (int t = 0; t < 4; ++t)                        \
            _Pragma("unroll") for (int j = 0; j < 2; ++j)                    \
        acc[(ibase) + t][(j0) + j] = __builtin_amdgcn_mfma_i32_16x16x64_i8(  \
            av[kh][t], bv[kh][(j0) + j], acc[(ibase) + t][(j0) + j], 0, 0,   \
            0);                                                              \
    __builtin_amdgcn_s_setprio(0);                                           \
  } while (0)

  // One tile, barrier-light. TOPW = tile-top vmcnt wait. S0..S3 = stages.
#define DO_TILE(AS, BS, TOPW, S0, S1, S2, S3)                                \
  do {                                                                       \
    const signed char* as = (AS);                                            \
    const signed char* bs = (BS);                                            \
    i32x4 av[2][4], bv[2][4];                                                \
    TOPW();                                                                  \
    __builtin_amdgcn_s_barrier();                                            \
    LDA(0);                                                                  \
    LDB(0);                                                                  \
    LDB(1);                                                                  \
    S0;                                                                      \
    MFMA16(0, 0); /* p0: A_lo x B0 */                                        \
    __builtin_amdgcn_s_barrier();                                            \
    S1;                                                                      \
    MFMA16(0, 2); /* p1: A_lo x B1 */                                        \
    LDA(1);       /* overwrite av with A_hi (issues after p1 by reg WAR) */  \
    __builtin_amdgcn_s_barrier();                                            \
    S2;                                                                      \
    MFMA16(4, 2); /* p2: A_hi x B1 */                                        \
    __builtin_amdgcn_s_barrier();                                            \
    S3;                                                                      \
    MFMA16(4, 0); /* p3: A_hi x B0 */                                        \
  } while (0)

  // Prologue: stage S[0..6] = tile0 {A_lo,B_0,B_1,A_hi} + tile1
  // {A_lo,B_0,B_1}. Tile 0's top wait/barrier handles the sync.
  stageA(0, 0, 0);
  stageB(0, 0, 0);
  stageB(0, 0, 1);
  stageA(0, 0, 1);
  stageA(1, BKB, 0);
  stageB(1, BKB, 0);
  stageB(1, BKB, 1);

#pragma unroll 2
  for (int kt = 0; kt < KTILES - 2; ++kt) {
    const int buf = kt & 1;
    const int k1 = (kt + 1) * BKB;
    const int k2 = (kt + 2) * BKB;
    DO_TILE(As[buf], Bs[buf], wait_vm6,
            (stageA(buf ^ 1, k1, 1)),   // S[4t+7]  = A_hi(t+1)
            (stageA(buf, k2, 0)),       // S[4t+8]  = A_lo(t+2)
            (stageB(buf, k2, 0)),       // S[4t+9]  = B_0 (t+2)
            (stageB(buf, k2, 1)));      // S[4t+10] = B_1 (t+2)
  }

  // Tail: tile 30 (stage only S0 = A_hi(31) = S[127]; top wait vmcnt(6)
  // valid: 254 units issued, need through 248), tile 31 (wait vmcnt(0)).
  DO_TILE(As[0], Bs[0], wait_vm6, (stageA(1, 31 * BKB, 1)), (void)0, (void)0,
          (void)0);
  DO_TILE(As[1], Bs[1], wait_vm0, (void)0, (void)0, (void)0, (void)0);

#undef LDA
#undef LDB
#undef MFMA16
#undef DO_TILE

  // Epilogue: y = a_m*accf + b_m + bias[n], a_m = scale*sx[m],
  // b_m = scale*sx[m]*(128-zp)*rs[m].
  const float scale = scale_p[0];
  const float c1 = 128.f - zp_p[0];
#pragma unroll
  for (int i = 0; i < 8; ++i) {
    const size_t mbase = m0 + wm * 128 + i * 16 + quad * 4;
    float am[4], bmv[4];
#pragma unroll
    for (int r = 0; r < 4; ++r) {
      const float a = scale * sx[mbase + r];
      am[r] = a;
      bmv[r] = a * c1 * rs[mbase + r];
    }
#pragma unroll
    for (int j = 0; j < 4; ++j) {
      const size_t n = n0 + wn * 64 + j * 16 + lrow;
      const float bv = bias[n];
#pragma unroll
      for (int r = 0; r < 4; ++r) {
        C[(mbase + r) * N_DIM + n] =
            fmaf(am[r], (float)acc[i][j][r], bmv[r] + bv);
      }
    }
  }
}

// ---------------------------------------------------------------------------
extern "C" void kernel_launch(void* const* d_in, const int* in_sizes, int n_in,
                              void* d_out, int out_size, void* d_ws,
                              size_t ws_size, hipStream_t stream) {
  const float* x = (const float*)d_in[0];
  const int* q = (const int*)d_in[1];
  const float* scale = (const float*)d_in[2];
  const float* zp = (const float*)d_in[3];
  const float* bias = (const float*)d_in[4];
  float* out = (float*)d_out;

  char* ws = (char*)d_ws;
  signed char* xi = (signed char*)ws;                           // 16 MB
  signed char* qsT = (signed char*)(ws + ((size_t)16 << 20));   // 16 MB
  float* sx = (float*)(ws + ((size_t)32 << 20));                // 16 KB
  float* rs = (float*)(ws + ((size_t)32 << 20) + (16 << 10));   // 16 KB

  convert_fused<<<8192, 256, 0, stream>>>(x, xi, sx, rs, q, qsT);
  gemm_kernel<<<256, 512, 0, stream>>>(xi, qsT, bias, sx, rs, scale, zp, out);
}

// Round 6
// 240.097 us; speedup vs baseline: 1.0675x; 1.0024x over previous
//
#include <hip/hip_runtime.h>
#include <cstdint>
#include <cstddef>

#define M_DIM 4096   // B*S
#define N_DIM 4096   // DOUT
#define K_DIM 4096   // DIN
#define BM 256
#define BN 256
#define BKB 128      // K-tile in BYTES (= 128 i8 elems); 128B LDS rows
#define KTILES (K_DIM / BKB)

typedef __attribute__((ext_vector_type(4))) int i32x4;

// async global->LDS, 16B per lane. LDS dest is wave-uniform base + lane*16.
__device__ __forceinline__ void async_copy16(const void* g, void* l) {
  __builtin_amdgcn_global_load_lds(
      (const __attribute__((address_space(1))) void*)g,
      (__attribute__((address_space(3))) void*)l,
      16, 0, 0);
}

__device__ __forceinline__ void wait_vm6() {
  asm volatile("s_waitcnt vmcnt(6)" ::: "memory");
}
__device__ __forceinline__ void wait_vm0() {
  asm volatile("s_waitcnt vmcnt(0)" ::: "memory");
}

// ---------------------------------------------------------------------------
// Fused convert kernel (from R5, neutral-kept): blocks [0,4096) = convert_w,
// blocks [4096,8192) = convert_x. Both verified bodies.
// ---------------------------------------------------------------------------
__global__ __launch_bounds__(256) void convert_fused(
    const float* __restrict__ x, signed char* __restrict__ xi,
    float* __restrict__ sx, float* __restrict__ rs,
    const int* __restrict__ q, signed char* __restrict__ qsT) {
  __shared__ __align__(16) int smem[64 * 68];  // 17408 B
  const int t = threadIdx.x;

  if (blockIdx.x < 4096) {
    // ---------------- convert_w body ---------------------------------------
    int(*qtile)[68] = (int(*)[68])smem;
    const int bid = blockIdx.x;
    const int k0 = (bid & 63) << 6;
    const int n0 = (bid >> 6) << 6;

    {
      const int c = t & 15;        // n-chunk (4 ints)
      const int r0 = t >> 4;       // k-row base
#pragma unroll
      for (int i = 0; i < 4; ++i) {
        const int r = r0 + i * 16;
        const int4 v =
            *(const int4*)(q + (size_t)(k0 + r) * N_DIM + n0 + c * 4);
        *(int4*)&qtile[r][c * 4] = v;
      }
    }
    __syncthreads();
    {
      const int kc = t & 15;   // k-chunk: rows kc*4 .. kc*4+3
      const int g = t >> 4;    // n-group: cols g*4 .. g*4+3
      int4 v[4];
#pragma unroll
      for (int i = 0; i < 4; ++i)
        v[i] = *(const int4*)&qtile[kc * 4 + i][g * 4];
#pragma unroll
      for (int j = 0; j < 4; ++j) {
        const int b0 = ((&v[0].x)[j] - 128) & 255;
        const int b1 = ((&v[1].x)[j] - 128) & 255;
        const int b2 = ((&v[2].x)[j] - 128) & 255;
        const int b3 = ((&v[3].x)[j] - 128) & 255;
        const int pk = b0 | (b1 << 8) | (b2 << 16) | (b3 << 24);
        *(int*)(qsT + (size_t)(n0 + g * 4 + j) * K_DIM + k0 + kc * 4) = pk;
      }
    }
  } else {
    // ---------------- convert_x body ---------------------------------------
    float* red = (float*)smem;
    const size_t row = blockIdx.x - 4096;
    const float* xr = x + row * (size_t)K_DIM;

    float4 v[4];
    float amax = 0.f;
#pragma unroll
    for (int i = 0; i < 4; ++i) {
      v[i] = *(const float4*)(xr + (i * 256 + t) * 4);
      amax = fmaxf(amax, fmaxf(fmaxf(fabsf(v[i].x), fabsf(v[i].y)),
                               fmaxf(fabsf(v[i].z), fabsf(v[i].w))));
    }
#pragma unroll
    for (int o = 32; o > 0; o >>= 1)
      amax = fmaxf(amax, __shfl_down(amax, o, 64));
    if ((t & 63) == 0) red[t >> 6] = amax;
    __syncthreads();
    amax = fmaxf(fmaxf(fmaxf(red[0], red[1]), fmaxf(red[2], red[3])), 1e-20f);
    const float inv = 127.f / amax;

    int ssum = 0;
    signed char* out = xi + row * (size_t)K_DIM;
#pragma unroll
    for (int i = 0; i < 4; ++i) {
      const int ia = __float2int_rn(v[i].x * inv);
      const int ib = __float2int_rn(v[i].y * inv);
      const int ic = __float2int_rn(v[i].z * inv);
      const int id = __float2int_rn(v[i].w * inv);
      ssum += ia + ib + ic + id;
      const int pk =
          (ia & 255) | ((ib & 255) << 8) | ((ic & 255) << 16) | (id << 24);
      *(int*)(out + (i * 256 + t) * 4) = pk;
    }
    float fs = (float)ssum;
#pragma unroll
    for (int o = 32; o > 0; o >>= 1) fs += __shfl_down(fs, o, 64);
    if ((t & 63) == 0) red[4 + (t >> 6)] = fs;
    __syncthreads();
    if (t == 0) {
      rs[row] = red[4] + red[5] + red[6] + red[7];
      sx[row] = amax * (1.f / 127.f);
    }
  }
}

// ---------------------------------------------------------------------------
// Kernel 3: 256x256 i8 GEMM. R6 change: 2 barriers per tile (was 4).
//
// Ledger (R2-verified): half-tile staging order per tile t:
//   S[4t+0]=A_lo(t)  S[4t+1]=B_0(t)  S[4t+2]=B_1(t)  S[4t+3]=A_hi(t)
// Stage placement at tile t: S0 = A_hi(t+1)->buf^1 at tile top (pre-p0);
// S1,S2,S3 = A_lo/B_0/B_1(t+2)->buf together after the mid barrier.
// Tile-top wait vmcnt(6): issued-so-far ends [S0(t-1)=A_hi(t), S1..S3(t-1)];
// allowing 3 units (6 loads) outstanding => landed through A_hi(t) => ALL of
// tile t resident at tile top.
//
// Barrier audit (only 2 are load-bearing):
//   TOP barrier of t: fences S0(t) [overwrites A_hi(t-1) region of buf^1,
//     whose reads were consumed by p2/p3 of t-1] and publishes residency.
//   MID barrier of t (after p1): fences S1,S2,S3 [overwrite A_lo/B0/B1(t)
//     regions, whose tile-top ds_reads were data-consumed by p0/p1 MFMAs
//     => lgkm drained before each wave reaches the barrier].
//   A_hi(t)'s reads (LDA(1), issued just before the mid barrier) are not
//     overwritten by S1..S3 (disjoint rows); their overwriter is S0(t+1),
//     fenced by t+1's TOP barrier after p2/p3 of t consumed them.
// p0/p1 and p2/p3 each form a contiguous 32-MFMA run under one setprio
// window. av registers reused for A_lo then A_hi (reg WAR; keeps
// arch-VGPR+acc at the 256/wave budget for 8 waves/CU).
// ---------------------------------------------------------------------------
__global__ __launch_bounds__(512, 2) void gemm_kernel(
    const signed char* __restrict__ A,   // [M][K] i8
    const signed char* __restrict__ Bt,  // [N][K] i8
    const float* __restrict__ bias, const float* __restrict__ sx,
    const float* __restrict__ rs, const float* __restrict__ scale_p,
    const float* __restrict__ zp_p, float* __restrict__ C) {
  __shared__ __align__(16) signed char As[2][BM * BKB];  // 2 x 32 KB
  __shared__ __align__(16) signed char Bs[2][BN * BKB];  // 2 x 32 KB

  const int tid = threadIdx.x;
  const int wave = tid >> 6;   // 0..7
  const int lane = tid & 63;
  const int wm = wave >> 2;    // 0..1  (M half)
  const int wn = wave & 3;     // 0..3  (N quarter)

  // T1: XCD-aware bijective swizzle; grid=256, 32 consecutive per XCD.
  const int swz = (blockIdx.x & 7) * 32 + (blockIdx.x >> 3);
  const int bm = swz & 15;
  const int bn = swz >> 4;
  const size_t m0 = (size_t)bm * BM;
  const size_t n0 = (size_t)bn * BN;

  // staging lane decomposition: LDS dest linear, global src pre-swizzled.
  const int srow = lane >> 3;                   // 0..7 row within 1KB issue
  const int schunk = (lane & 7) ^ srow;         // swizzled global 16B chunk

  // fragment lane decomposition (16x16x64)
  const int quad = lane >> 4;
  const int lrow = lane & 15;
  const int rsw = lrow & 7;

  const signed char* Abase = A + m0 * K_DIM + schunk * 16;
  const signed char* Bbase = Bt + n0 * K_DIM + schunk * 16;

  i32x4 acc[8][4];
  const i32x4 zero = {0, 0, 0, 0};
#pragma unroll
  for (int i = 0; i < 8; ++i)
#pragma unroll
    for (int j = 0; j < 4; ++j) acc[i][j] = zero;

  // Half-tile stagers: each = 2 global_load_lds per lane (16 KB total).
  auto stageA = [&](int b, int k0, int ig) {
#pragma unroll
    for (int i = 0; i < 2; ++i) {
      const int rbase = i * 128 + ig * 64 + wave * 8;  // wave-uniform
      const size_t go = (size_t)(rbase + srow) * K_DIM + k0;
      async_copy16(Abase + go, (void*)&As[b][rbase * BKB]);
    }
  };
  auto stageB = [&](int b, int k0, int jg) {
#pragma unroll
    for (int i = 0; i < 2; ++i) {
      const int rbase = (i * 2 + (wave >> 2)) * 64 + jg * 32 + (wave & 3) * 8;
      const size_t go = (size_t)(rbase + srow) * K_DIM + k0;
      async_copy16(Bbase + go, (void*)&Bs[b][rbase * BKB]);
    }
  };

#define LDA(ig)                                                              \
  do {                                                                       \
    _Pragma("unroll") for (int kh = 0; kh < 2; ++kh)                         \
        _Pragma("unroll") for (int t = 0; t < 4; ++t) {                      \
      const int ar = wm * 128 + (ig) * 64 + t * 16 + lrow;                   \
      av[kh][t] =                                                            \
          *(const i32x4*)(as + ar * BKB + ((((kh << 2) | quad) ^ rsw) << 4));\
    }                                                                        \
  } while (0)

#define LDB(jg)                                                              \
  do {                                                                       \
    _Pragma("unroll") for (int kh = 0; kh < 2; ++kh)                         \
        _Pragma("unroll") for (int t = 0; t < 2; ++t) {                      \
      const int br = wn * 64 + ((jg) * 2 + t) * 16 + lrow;                   \
      bv[kh][(jg) * 2 + t] =                                                 \
          *(const i32x4*)(bs + br * BKB + ((((kh << 2) | quad) ^ rsw) << 4));\
    }                                                                        \
  } while (0)

#define MFMA16(ibase, j0)                                                    \
  do {                                                                       \
    _Pragma("unroll") for (int kh = 0; kh < 2; ++kh)                         \
        _Pragma("unroll") for (int t = 0; t < 4; ++t)                        \
            _Pragma("unroll") for (int j = 0; j < 2; ++j)                    \
        acc[(ibase) + t][(j0) + j] = __builtin_amdgcn_mfma_i32_16x16x64_i8(  \
            av[kh][t], bv[kh][(j0) + j], acc[(ibase) + t][(j0) + j], 0, 0,   \
            0);                                                              \
  } while (0)

  // One tile: 2 barriers, 1 vmcnt. S0 = A_hi(t+1) stage (top), S123 =
  // A_lo/B0/B1(t+2) stages (after mid barrier).
#define DO_TILE(AS, BS, TOPW, S0, S123)                                      \
  do {                                                                       \
    const signed char* as = (AS);                                            \
    const signed char* bs = (BS);                                            \
    i32x4 av[2][4], bv[2][4];                                                \
    TOPW();                                                                  \
    __builtin_amdgcn_s_barrier();                                            \
    LDA(0);                                                                  \
    LDB(0);                                                                  \
    LDB(1);                                                                  \
    S0;                                                                      \
    __builtin_amdgcn_s_setprio(1);                                           \
    MFMA16(0, 0); /* p0: A_lo x B0 */                                        \
    MFMA16(0, 2); /* p1: A_lo x B1 */                                        \
    __builtin_amdgcn_s_setprio(0);                                           \
    LDA(1);       /* av <- A_hi (reg WAR vs p0/p1; LDS src resident) */      \
    __builtin_amdgcn_s_barrier();                                            \
    S123;                                                                    \
    __builtin_amdgcn_s_setprio(1);                                           \
    MFMA16(4, 2); /* p2: A_hi x B1 */                                        \
    MFMA16(4, 0); /* p3: A_hi x B0 */                                        \
    __builtin_amdgcn_s_setprio(0);                                           \
  } while (0)

  // Prologue: stage units 1..7 = tile0 {A_lo,B_0,B_1,A_hi} + tile1
  // {A_lo,B_0,B_1}; tile 0's top vmcnt(6) lands through A_hi(0).
  stageA(0, 0, 0);
  stageB(0, 0, 0);
  stageB(0, 0, 1);
  stageA(0, 0, 1);
  stageA(1, BKB, 0);
  stageB(1, BKB, 0);
  stageB(1, BKB, 1);

#pragma unroll 2
  for (int kt = 0; kt < KTILES - 2; ++kt) {
    const int buf = kt & 1;
    const int k1 = (kt + 1) * BKB;
    const int k2 = (kt + 2) * BKB;
    DO_TILE(As[buf], Bs[buf], wait_vm6,
            (stageA(buf ^ 1, k1, 1)),                 // S0 = A_hi(t+1)
            (stageA(buf, k2, 0), stageB(buf, k2, 0),  // S1,S2 = A_lo,B0(t+2)
             stageB(buf, k2, 1)));                    // S3 = B_1(t+2)
  }

  // Tail: tile 30 (S0 = A_hi(31), no S123; top vmcnt(6) lands through
  // A_hi(30)), tile 31 (top vmcnt(0), no stages).
  DO_TILE(As[0], Bs[0], wait_vm6, (stageA(1, 31 * BKB, 1)), (void)0);
  DO_TILE(As[1], Bs[1], wait_vm0, (void)0, (void)0);

#undef LDA
#undef LDB
#undef MFMA16
#undef DO_TILE

  // Epilogue: y = a_m*accf + b_m + bias[n], a_m = scale*sx[m],
  // b_m = scale*sx[m]*(128-zp)*rs[m].
  const float scale = scale_p[0];
  const float c1 = 128.f - zp_p[0];
#pragma unroll
  for (int i = 0; i < 8; ++i) {
    const size_t mbase = m0 + wm * 128 + i * 16 + quad * 4;
    float am[4], bmv[4];
#pragma unroll
    for (int r = 0; r < 4; ++r) {
      const float a = scale * sx[mbase + r];
      am[r] = a;
      bmv[r] = a * c1 * rs[mbase + r];
    }
#pragma unroll
    for (int j = 0; j < 4; ++j) {
      const size_t n = n0 + wn * 64 + j * 16 + lrow;
      const float bv = bias[n];
#pragma unroll
      for (int r = 0; r < 4; ++r) {
        C[(mbase + r) * N_DIM + n] =
            fmaf(am[r], (float)acc[i][j][r], bmv[r] + bv);
      }
    }
  }
}

// ---------------------------------------------------------------------------
extern "C" void kernel_launch(void* const* d_in, const int* in_sizes, int n_in,
                              void* d_out, int out_size, void* d_ws,
                              size_t ws_size, hipStream_t stream) {
  const float* x = (const float*)d_in[0];
  const int* q = (const int*)d_in[1];
  const float* scale = (const float*)d_in[2];
  const float* zp = (const float*)d_in[3];
  const float* bias = (const float*)d_in[4];
  float* out = (float*)d_out;

  char* ws = (char*)d_ws;
  signed char* xi = (signed char*)ws;                           // 16 MB
  signed char* qsT = (signed char*)(ws + ((size_t)16 << 20));   // 16 MB
  float* sx = (float*)(ws + ((size_t)32 << 20));                // 16 KB
  float* rs = (float*)(ws + ((size_t)32 << 20) + (16 << 10));   // 16 KB

  convert_fused<<<8192, 256, 0, stream>>>(x, xi, sx, rs, q, qsT);
  gemm_kernel<<<256, 512, 0, stream>>>(xi, qsT, bias, sx, rs, scale, zp, out);
}